// Round 6
// baseline (525.406 us; speedup 1.0000x reference)
//
#include <hip/hip_runtime.h>

typedef _Float16 half8 __attribute__((ext_vector_type(8)));
typedef float floatx16 __attribute__((ext_vector_type(16)));

constexpr int Gn = 5;
constexpr int Bn = 131072;
constexpr int Kn = 512;
constexpr int Dn = 64;

constexpr long long QOFF = (long long)Gn * Bn * Dn;  // end of quantized block
constexpr long long IOFF = QOFF + Gn + 1;            // start of indices block
constexpr unsigned CAPE = 49152;                     // rescue-entry capacity

// async global->LDS, 16B per lane; dest = wave-uniform base + lane*16
#define GLDS(gp, lp)  __builtin_amdgcn_global_load_lds( \
    (const __attribute__((address_space(1))) void*)(gp), \
    (__attribute__((address_space(3))) void*)(lp), 16, 0, 0)

// ---------------------------------------------------------------------------
// Prep: esq (bit-exact round-1 accumulation order — rescue depends on it),
// fp16 codebook ch16 (linear layout), and esqt = fp16(-esq*1024) stored
// TRANSPOSED: esqt[g][code&31][code>>5] so screen loads 16 chunk-values of
// its code-slot as one contiguous 32B read. Bias folds -esq/2 into the MFMA
// via a 2^-11 B-slot (1024 * 2^-11 = 1/2).
// ---------------------------------------------------------------------------
__global__ void vq_prep(const float* __restrict__ code, float* __restrict__ esq,
                        _Float16* __restrict__ ch16, _Float16* __restrict__ esqt) {
    int i = blockIdx.x * blockDim.x + threadIdx.x;
    if (i >= Gn * Kn) return;
    const float4* c4 = reinterpret_cast<const float4*>(code + (long long)i * Dn);
    _Float16* hp = ch16 + (long long)i * Dn;
    float s0 = 0.f, s1 = 0.f, s2 = 0.f, s3 = 0.f;
#pragma unroll
    for (int j = 0; j < 16; ++j) {
        float4 v = c4[j];
        s0 += v.x * v.x; s1 += v.y * v.y; s2 += v.z * v.z; s3 += v.w * v.w;
        hp[4 * j + 0] = (_Float16)v.x;
        hp[4 * j + 1] = (_Float16)v.y;
        hp[4 * j + 2] = (_Float16)v.z;
        hp[4 * j + 3] = (_Float16)v.w;
    }
    float e = (s0 + s1) + (s2 + s3);
    esq[i] = e;
    int g = i >> 9, k = i & 511;
    esqt[(g << 9) + ((k & 31) << 4) + (k >> 5)] = (_Float16)(-(e * 1024.0f));
}

// ---------------------------------------------------------------------------
// LDS-staged transposed-MFMA screening, 4-chunk phases.
//   A = codebook chunk (m = code, from LDS), B = two feature tiles (n = row).
//   acc_t = dot - esq/2 via 4 dot MFMAs + 1 bias MFMA per chunk, two
//   independent chains for ILP. 64 rows/wave, 4 waves share staged chunks.
// Phases: 4 phases x 4 chunks. LDS = 2 x 16KB double buffer. Per phase:
//   issue 4 global_load_lds (next phase) -> compute 4 chunks -> barrier.
//   Barrier convoy count drops 16 -> 4; compiler's vmcnt(0)+lgkmcnt(0)
//   drain before s_barrier is exactly the wait the 1-ahead pipeline needs.
// Staging swizzle on the GLOBAL source (u^cs involution), LDS dest linear
//   (both-sides-or-neither); LDS layout identical to reg-staged round 3.
// Tracking: per lane top-2, 8-bit (chunk<<4|reg) id in mantissa LSBs, SPLIT
//   into two chains (r<8 / r>=8) to halve the serial med3/max latency,
//   merged at the end; then one shfl_xor(32) cross-half merge.
// ---------------------------------------------------------------------------
__global__ __launch_bounds__(256, 4) void vq_screen(
    const float* __restrict__ feat, const float* __restrict__ codef,
    const _Float16* __restrict__ ch16, const _Float16* __restrict__ esqt,
    float* __restrict__ out, float* __restrict__ accg,
    unsigned* __restrict__ cnt, unsigned* __restrict__ entries)
{
    __shared__ float4 smf[2 * 1024];   // [buf][4 chunks][32 codes][8 units] = 2 x 16KB

    const int g = blockIdx.y;
    const int lane = threadIdx.x & 63;
    const int wv = threadIdx.x >> 6;
    const int l31 = lane & 31;
    const int hh = lane >> 5;
    const long long rowbase = (long long)blockIdx.x * 256 + wv * 64;
    const float MARGIN = 3.0e-5f;   // mdist units; err-diff rms ~5e-6 -> ~6 sigma
    const int CLR = (int)0xFFFFFF00;

    // ---- feature staging: 2 tiles x 32 rows; B layout n=l31, k=8*hh+j+16*s
    half8 fH[2][4]; float xs[2];
#pragma unroll
    for (int t = 0; t < 2; ++t) {
        const float* rp = feat + ((long long)g * Bn + rowbase + t * 32 + l31) * Dn + hh * 8;
        float x = 0.f;
#pragma unroll
        for (int s = 0; s < 4; ++s) {
            float4 u0 = *(const float4*)(rp + 16 * s);
            float4 u1 = *(const float4*)(rp + 16 * s + 4);
            half8 h;
            h[0] = (_Float16)u0.x; h[1] = (_Float16)u0.y;
            h[2] = (_Float16)u0.z; h[3] = (_Float16)u0.w;
            h[4] = (_Float16)u1.x; h[5] = (_Float16)u1.y;
            h[6] = (_Float16)u1.z; h[7] = (_Float16)u1.w;
            fH[t][s] = h;
            x += u0.x*u0.x + u0.y*u0.y + u0.z*u0.z + u0.w*u0.w
               + u1.x*u1.x + u1.y*u1.y + u1.z*u1.z + u1.w*u1.w;
        }
        xs[t] = x + __shfl_xor(x, 32);
    }

    // ---- esq bias values: 16 chunk-values for this lane's code slot -------
    const half8* evp = (const half8*)(esqt + ((long long)g << 9) + l31 * 16);
    half8 ev0 = evp[0], ev1 = evp[1];

    // bias B-frag: 2^-11 in k==0 slot (hh==0, j==0), zero elsewhere
    half8 b5 = {(_Float16)0.f};
    b5[0] = hh ? (_Float16)0.f : (_Float16)4.8828125e-4f;

    // ---- staging addresses ------------------------------------------------
    const int cs = lane >> 3;            // 0..7: code sub-index in wave's 8 codes
    const int u  = lane & 7;             // 16B unit within code row
    const int codeLocal = wv * 8 + cs;   // 0..31 (codeLocal & 7 == cs)
    const float4* srcF4 = (const float4*)(ch16 + ((long long)g * Kn) * Dn);
    // pre-swizzled global source; LDS dest linear (unit codeLocal*8 + u)
    const float4* gsrc = srcF4 + codeLocal * 8 + (u ^ cs);
    const int rb0 = l31 * 8;
    const int rsw = l31 & 7;

    // ---- prologue: chunks 0..3 -> buf0 ------------------------------------
#pragma unroll
    for (int s4 = 0; s4 < 4; ++s4)
        GLDS(gsrc + s4 * 256, &smf[s4 * 256 + wv * 64]);
    __syncthreads();   // compiler drains vmcnt(0) before the barrier

    // split top-2 chains: [tile][r-half]
    float v1h[2][2] = {{-3.0e38f, -3.0e38f}, {-3.0e38f, -3.0e38f}};
    float v2h[2][2] = {{-3.0e38f, -3.0e38f}, {-3.0e38f, -3.0e38f}};

#pragma unroll
    for (int p = 0; p < 4; ++p) {
        const int buf = (p & 1) * 1024;
        if (p < 3) {
#pragma unroll
            for (int s4 = 0; s4 < 4; ++s4)
                GLDS(gsrc + ((p + 1) * 4 + s4) * 256,
                     &smf[((p + 1) & 1) * 1024 + s4 * 256 + wv * 64]);
        }
#pragma unroll
        for (int s4 = 0; s4 < 4; ++s4) {
            const int ch = p * 4 + s4;
            const int cb = buf + s4 * 256;

            half8 cH[4];
#pragma unroll
            for (int s = 0; s < 4; ++s)
                cH[s] = *(const half8*)&smf[cb + rb0 + ((hh + 2 * s) ^ rsw)];

            half8 a5 = {(_Float16)0.f};
            _Float16 eb = (ch & 8) ? ev1[ch & 7] : ev0[ch & 7];
            a5[0] = hh ? (_Float16)0.f : eb;   // -esq*1024 in k==0 slot

            floatx16 acc0 = {0.f}, acc1 = {0.f};
#pragma unroll
            for (int s = 0; s < 4; ++s) {
                acc0 = __builtin_amdgcn_mfma_f32_32x32x16_f16(cH[s], fH[0][s], acc0, 0, 0, 0);
                acc1 = __builtin_amdgcn_mfma_f32_32x32x16_f16(cH[s], fH[1][s], acc1, 0, 0, 0);
            }
            acc0 = __builtin_amdgcn_mfma_f32_32x32x16_f16(a5, b5, acc0, 0, 0, 0);
            acc1 = __builtin_amdgcn_mfma_f32_32x32x16_f16(a5, b5, acc1, 0, 0, 0);

            const int idb = ch << 4;
#pragma unroll
            for (int r = 0; r < 16; ++r) {
                const int hc = r >> 3;
                float c0 = __int_as_float((__float_as_int(acc0[r]) & CLR) | (idb | r));
                v2h[0][hc] = __builtin_amdgcn_fmed3f(v1h[0][hc], v2h[0][hc], c0);
                v1h[0][hc] = fmaxf(v1h[0][hc], c0);
                float c1 = __int_as_float((__float_as_int(acc1[r]) & CLR) | (idb | r));
                v2h[1][hc] = __builtin_amdgcn_fmed3f(v1h[1][hc], v2h[1][hc], c1);
                v1h[1][hc] = fmaxf(v1h[1][hc], c1);
            }
        }
        if (p < 3) __syncthreads();   // protects buf reuse; drains next-phase loads
    }

    // ---- merge split chains, then the two half-wave code subsets ----------
    int codew[2]; float v1c[2], v2c[2];
#pragma unroll
    for (int t = 0; t < 2; ++t) {
        float a1 = v1h[t][0], b1 = v1h[t][1];
        float v1 = fmaxf(a1, b1);
        float v2 = fmaxf(fminf(a1, b1), fmaxf(v2h[t][0], v2h[t][1]));

        float o1 = __shfl_xor(v1, 32);
        float o2 = __shfl_xor(v2, 32);
        float w1 = fmaxf(v1, o1);
        float w2 = fmaxf(fminf(v1, o1), fmaxf(v2, o2));
        int hsrc = (o1 > v1) ? (hh ^ 1) : hh;   // equal packed => same (ch,r), flagged anyway
        int idw = __float_as_int(w1) & 255;
        int rr = idw & 15;
        // C/D row map: code_in_chunk = (r&3) + 8*(r>>2) + 4*hh_src
        codew[t] = ((idw >> 4) << 5) + (rr & 3) + 8 * (rr >> 2) + 4 * hsrc;
        v1c[t] = __int_as_float(__float_as_int(w1) & CLR);
        v2c[t] = __int_as_float(__float_as_int(w2) & CLR);
    }

    // ---- epilogue: coalesced gather (4 rows / iter, 1KB contiguous stores)
#pragma unroll
    for (int t = 0; t < 2; ++t) {
        float* obase = out + ((long long)g * Bn + rowbase + t * 32) * Dn;
#pragma unroll
        for (int i = 0; i < 8; ++i) {
            int r = i * 4 + (lane >> 4);
            int c = __shfl(codew[t], r);   // owner lane r (hh=0 copy)
            float4 q = *(const float4*)(codef + ((long long)(g * Kn + c)) * Dn + (lane & 15) * 4);
            *(float4*)(obase + (long long)r * Dn + (lane & 15) * 4) = q;
        }
    }

    // ---- indices, loss, rescue flags --------------------------------------
    float lsum = 0.f;
    bool fl[2] = {false, false};
    unsigned rw[2] = {0u, 0u};
#pragma unroll
    for (int t = 0; t < 2; ++t) {
        if (hh == 0) {
            long long grow = rowbase + t * 32 + l31;
            out[IOFF + (long long)g * Bn + grow] = (float)codew[t];
            lsum += xs[t] - 2.0f * v1c[t];            // xsq + esq - 2*dot
            fl[t] = (v1c[t] - v2c[t] <= MARGIN);
            rw[t] = (unsigned)grow;
        }
    }

    // ---- wave-aggregated rescue-entry append (<=1 atomic per wave) --------
    unsigned long long m0 = __ballot(fl[0]);
    unsigned long long m1 = __ballot(fl[1]);
    unsigned tot = (unsigned)(__builtin_popcountll(m0) + __builtin_popcountll(m1));
    if (tot) {
        unsigned base = 0;
        if (lane == 0) base = atomicAdd(cnt, tot);
        base = (unsigned)__shfl((int)base, 0);
        unsigned long long lt = ((unsigned long long)1 << lane) - 1;
        if (fl[0]) {
            unsigned s = base + (unsigned)__builtin_popcountll(m0 & lt);
            if (s < CAPE) entries[s] = ((unsigned)g << 17) | rw[0];
        }
        if (fl[1]) {
            unsigned s = base + (unsigned)__builtin_popcountll(m0)
                              + (unsigned)__builtin_popcountll(m1 & lt);
            if (s < CAPE) entries[s] = ((unsigned)g << 17) | rw[1];
        }
    }
#pragma unroll
    for (int m = 1; m < 64; m <<= 1) lsum += __shfl_xor(lsum, m);
    if (lane == 0) atomicAdd(&accg[g], lsum);
}

// ---------------------------------------------------------------------------
// Exact rescue: one wave per flagged row, full K=512 scan with round-1's
// bit-exact fp32 formula (pairwise-8 xsq, 4-acc fmaf dot, first-index ties).
// Finalize fused in (block 0 lane 0) — acc is complete before this launch.
// ---------------------------------------------------------------------------
__global__ __launch_bounds__(256) void vq_rescue(
    const float* __restrict__ feat, const float* __restrict__ codef,
    const float* __restrict__ esq, const unsigned* __restrict__ cnt,
    const unsigned* __restrict__ entries, float* __restrict__ out,
    const float* __restrict__ accg)
{
    if (blockIdx.x == 0 && threadIdx.x == 0) {
        float tot = 0.f;
#pragma unroll
        for (int g = 0; g < Gn; ++g) {
            float m = accg[g] / 8388608.0f;
            float l = m + 0.25f * m;
            out[QOFF + g] = l;
            tot += l;
        }
        out[QOFF + Gn] = tot;
    }

    const int lane = threadIdx.x & 63;
    const int wid = blockIdx.x * 4 + (threadIdx.x >> 6);
    const int nw = gridDim.x * 4;
    const int n = (int)min(*cnt, CAPE);

    for (int i = wid; i < n; i += nw) {
        unsigned e = entries[i];
        int g = e >> 17;
        long long b = e & 131071u;

        const float* xp = feat + ((long long)g * Bn + b) * Dn;
        float x[64];
#pragma unroll
        for (int j = 0; j < 16; ++j) {
            float4 u = ((const float4*)xp)[j];
            x[4*j] = u.x; x[4*j+1] = u.y; x[4*j+2] = u.z; x[4*j+3] = u.w;
        }
        float xsq;
        {
#pragma clang fp contract(off)
            float r0[8];
#pragma unroll
            for (int j = 0; j < 8; ++j) r0[j] = x[j] * x[j];
#pragma unroll
            for (int q = 8; q < 64; q += 8)
#pragma unroll
                for (int j = 0; j < 8; ++j) {
                    float s0 = x[q + j] * x[q + j];
                    r0[j] = r0[j] + s0;
                }
            xsq = ((r0[0] + r0[1]) + (r0[2] + r0[3])) + ((r0[4] + r0[5]) + (r0[6] + r0[7]));
        }

        const float* cg = codef + (long long)g * Kn * Dn;
        const float* eg = esq + g * Kn;
        float best = 3.4e38f; int bk = 0x7fffffff;
        for (int j = 0; j < 8; ++j) {
            int k = j * 64 + lane;
            const float4* cp = (const float4*)(cg + (long long)k * Dn);
            float d0 = 0.f, d1 = 0.f, d2 = 0.f, d3 = 0.f;
#pragma unroll
            for (int q = 0; q < 16; ++q) {
                float4 v = cp[q];
                d0 = fmaf(v.x, x[4*q+0], d0);
                d1 = fmaf(v.y, x[4*q+1], d1);
                d2 = fmaf(v.z, x[4*q+2], d2);
                d3 = fmaf(v.w, x[4*q+3], d3);
            }
            float dot = (d0 + d1) + (d2 + d3);
            float dist = (xsq + eg[k]) - 2.0f * dot;
            if (dist < best) { best = dist; bk = k; }
        }
#pragma unroll
        for (int m = 1; m < 64; m <<= 1) {
            float ov = __shfl_xor(best, m);
            int   ok = __shfl_xor(bk, m);
            if (ov < best || (ov == best && ok < bk)) { best = ov; bk = ok; }
        }
        if (lane == 0) out[IOFF + (long long)g * Bn + b] = (float)bk;
        out[((long long)g * Bn + b) * Dn + lane] = cg[(long long)bk * Dn + lane];
    }
}

extern "C" void kernel_launch(void* const* d_in, const int* in_sizes, int n_in,
                              void* d_out, int out_size, void* d_ws, size_t ws_size,
                              hipStream_t stream) {
    const float* feat = (const float*)d_in[0];   // [G,B,D] fp32
    const float* code = (const float*)d_in[1];   // [G,K,D] fp32
    float* out = (float*)d_out;

    char* w = (char*)d_ws;
    float*     acc     = (float*)w;                    // [0,64)
    unsigned*  cnt     = (unsigned*)(w + 64);          // [64,128)
    float*     esq     = (float*)(w + 128);            // 10240 B
    _Float16*  esqt    = (_Float16*)(w + 10368);       // 5120 B (16B-aligned)
    _Float16*  ch16    = (_Float16*)(w + 15488);       // 327680 B (16B-aligned)
    unsigned*  entries = (unsigned*)(w + 343168);      // 49152*4 = 196608 B (total 539776)

    hipMemsetAsync(w, 0, 128, stream);
    vq_prep<<<(Gn * Kn + 255) / 256, 256, 0, stream>>>(code, esq, ch16, esqt);
    dim3 grid(Bn / 256, Gn);
    vq_screen<<<grid, 256, 0, stream>>>(feat, code, ch16, esqt, out, acc, cnt, entries);
    vq_rescue<<<2048, 256, 0, stream>>>(feat, code, esq, cnt, entries, out, acc);
}